// Round 1
// 362.796 us; speedup vs baseline: 1.0036x; 1.0036x over previous
//
#include <hip/hip_runtime.h>

typedef _Float16 f16;
typedef _Float16 f16x8 __attribute__((ext_vector_type(8)));
typedef _Float16 f16x4 __attribute__((ext_vector_type(4)));
typedef float    f32x4 __attribute__((ext_vector_type(4)));
typedef float    f32x16 __attribute__((ext_vector_type(16)));

#define MROWS 8192      // B*S
#define KDIM  1024      // D
#define SEQ   2048
#define HDIM  64
#define QKV_LD 3072     // fused QKV leading dim

#if __has_builtin(__builtin_amdgcn_exp2f)
#define EXP2(x) __builtin_amdgcn_exp2f(x)
#else
#define EXP2(x) exp2f(x)
#endif

// 5-bit row mix: lanes n, n+8, n+16, n+24 get distinct keys (kills 4-way conflicts)
__device__ __forceinline__ int swz5(int row) { return (row ^ (row >> 3)) & 7; }

// ---------------- prep: fp32 -> fp16 cast, all three inputs in one launch ----------------
__global__ __launch_bounds__(256) void cast3_k(const float* __restrict__ a,
                                               const float* __restrict__ b,
                                               const float* __restrict__ c,
                                               f16* __restrict__ out) {
  int i = blockIdx.x * 256 + threadIdx.x;
  const float* src = (blockIdx.y == 0) ? a : (blockIdx.y == 1) ? b : c;
  float4 v = ((const float4*)src)[i];
  f16x4 o = { (f16)v.x, (f16)v.y, (f16)v.z, (f16)v.w };
  *(f16x4*)&out[(size_t)blockIdx.y * 8388608 + (size_t)i * 4] = o;
}

// ---------------- prep: transpose + cast weight [1024][1024] ----------------
__global__ __launch_bounds__(256) void transpose_cast_k(const float* __restrict__ w,
                                                        f16* __restrict__ wt) {
  __shared__ float t[32][33];
  int tx = threadIdx.x, ty = threadIdx.y;
  int bx = blockIdx.x * 32, by = blockIdx.y * 32;
  #pragma unroll
  for (int i = ty; i < 32; i += 8) t[i][tx] = w[(size_t)(by + i) * KDIM + bx + tx];
  __syncthreads();
  #pragma unroll
  for (int i = ty; i < 32; i += 8) wt[(size_t)(bx + i) * KDIM + by + tx] = (f16)t[tx][i];
}

// ---------------- prep: concat 3 bias vectors ----------------
__global__ __launch_bounds__(256) void concat3_k(const float* __restrict__ a,
                                                 const float* __restrict__ b,
                                                 const float* __restrict__ c,
                                                 float* __restrict__ o) {
  int i = blockIdx.x * 256 + threadIdx.x;   // 0..3071
  float v;
  if (i < 1024) v = a[i]; else if (i < 2048) v = b[i - 1024]; else v = c[i - 2048];
  o[i] = v;
}

// ---------------- GEMM: C[M x Ncols] = A[M x K] * Bt[N x K]^T + bias ----------------
template<bool OUT_F16>
__global__ __launch_bounds__(256) void gemm_k(const f16* __restrict__ A0, size_t aStride,
                                              const f16* __restrict__ Bt,
                                              const float* __restrict__ bias,
                                              void* __restrict__ Cout, int ldc) {
  __shared__ f16 sA[128 * 64];
  __shared__ f16 sB[128 * 64];
  const int tid  = threadIdx.x;
  const int lane = tid & 63;
  const int r    = lane & 15;
  const int q    = lane >> 4;
  const int wave = tid >> 6;
  const int m0 = blockIdx.x * 128;
  const int ng = blockIdx.z * 1024 + blockIdx.y * 128;
  const int wm = (wave >> 1) * 64;
  const int wn = (wave & 1) * 64;
  const f16* A = A0 + (size_t)blockIdx.z * aStride;

  f32x4 acc[4][4];
  #pragma unroll
  for (int i = 0; i < 4; ++i)
    #pragma unroll
    for (int j = 0; j < 4; ++j) acc[i][j] = (f32x4){0.f, 0.f, 0.f, 0.f};

  for (int kt = 0; kt < KDIM; kt += 64) {
    #pragma unroll
    for (int issue = 0; issue < 4; ++issue) {
      int g   = issue * 256 + tid;
      int row = g >> 3;
      int csw = (g & 7) ^ (row & 7);
      const f16* gA = A  + (size_t)(m0 + row) * KDIM + kt + csw * 8;
      const f16* gB = Bt + (size_t)(ng + row) * KDIM + kt + csw * 8;
      int lb = __builtin_amdgcn_readfirstlane((issue * 256 + (tid & ~63)) * 16);
      __builtin_amdgcn_global_load_lds((const __attribute__((address_space(1))) void*)gA,
                                       (__attribute__((address_space(3))) void*)((char*)sA + lb),
                                       16, 0, 0);
      __builtin_amdgcn_global_load_lds((const __attribute__((address_space(1))) void*)gB,
                                       (__attribute__((address_space(3))) void*)((char*)sB + lb),
                                       16, 0, 0);
    }
    __syncthreads();
    #pragma unroll
    for (int kk = 0; kk < 64; kk += 32) {
      f16x8 af[4], bf[4];
      #pragma unroll
      for (int mi = 0; mi < 4; ++mi) {
        int row = wm + mi * 16 + r;
        int cs  = ((kk >> 3) + q) ^ (row & 7);
        af[mi] = *(const f16x8*)&sA[row * 64 + cs * 8];
      }
      #pragma unroll
      for (int ni = 0; ni < 4; ++ni) {
        int row = wn + ni * 16 + r;
        int cs  = ((kk >> 3) + q) ^ (row & 7);
        bf[ni] = *(const f16x8*)&sB[row * 64 + cs * 8];
      }
      #pragma unroll
      for (int mi = 0; mi < 4; ++mi)
        #pragma unroll
        for (int ni = 0; ni < 4; ++ni)
          acc[mi][ni] = __builtin_amdgcn_mfma_f32_16x16x32_f16(af[mi], bf[ni], acc[mi][ni], 0, 0, 0);
    }
    __syncthreads();
  }
  #pragma unroll
  for (int ni = 0; ni < 4; ++ni) {
    int col = ng + wn + ni * 16 + r;
    float bv = bias[col];
    #pragma unroll
    for (int mi = 0; mi < 4; ++mi) {
      int rowb = m0 + wm + mi * 16 + q * 4;
      #pragma unroll
      for (int reg = 0; reg < 4; ++reg) {
        float v = acc[mi][ni][reg] + bv;
        if constexpr (OUT_F16) ((f16*)Cout)[(size_t)(rowb + reg) * ldc + col] = (f16)v;
        else                   ((float*)Cout)[(size_t)(rowb + reg) * ldc + col] = v;
      }
    }
  }
}

// ---------------- V transpose: QKV V-part -> Vt[b][h][64][2048] ----------------
__global__ __launch_bounds__(256) void vtrans_k(const f16* __restrict__ qkv,
                                                f16* __restrict__ vt) {
  __shared__ f16 t[64 * 64];
  const int tid = threadIdx.x;
  const int st = blockIdx.x, h = blockIdx.y, b = blockIdx.z;
  const f16* src = qkv + (size_t)(b * SEQ + st * 64) * QKV_LD + 2048 + h * HDIM;
  #pragma unroll
  for (int issue = 0; issue < 2; ++issue) {
    int g = issue * 256 + tid;
    int srow = g >> 3, c = g & 7;
    f16x8 v = *(const f16x8*)(src + (size_t)srow * QKV_LD + c * 8);
    *(f16x8*)&t[srow * 64 + (c ^ (srow & 7)) * 8] = v;
  }
  __syncthreads();
  f16* dst = vt + (size_t)(b * 16 + h) * HDIM * SEQ + st * 64;
  #pragma unroll
  for (int issue = 0; issue < 2; ++issue) {
    int g = issue * 256 + tid;
    int d = g >> 3, c8 = g & 7;
    f16x8 o;
    #pragma unroll
    for (int j = 0; j < 8; ++j) {
      int s = c8 * 8 + j;
      o[j] = t[s * 64 + ((d >> 3) ^ (s & 7)) * 8 + (d & 7)];
    }
    *(f16x8*)(dst + (size_t)d * SEQ + c8 * 8) = o;
  }
}

// ---------------- flash attention: transposed dataflow, 32x32x16 MFMA, ----------------
// double-buffered staging, 5-bit-mix swizzle, raw v_exp_f32 softmax.
// grid (qt=16, h=16, b=4), 256 thr = 4 waves, 32 q-rows/wave, 64-key tiles.
// NEW vs prev round:
//  (1) XCD-locality block remap: all 16 qt-blocks of one (h,b) share flat%8 -> same
//      XCD -> the 512KB K/V panel is fetched ~once per XCD instead of 8x (T1).
//  (2) s_setprio(1) around QK and PV MFMA clusters (T5: +4-7% on independent-block attn).
__global__ __launch_bounds__(256) void attn_k(const f16* __restrict__ qkv,
                                              const f16* __restrict__ vt,
                                              f16* __restrict__ ctx) {
  __shared__ f16 smem[16384];            // 32 KB: buf0 f16[0,8192) = sK|sV, buf1 [8192,16384)
  const int tid  = threadIdx.x;
  const int lane = tid & 63;
  const int wave = tid >> 6;
  const int n    = lane & 31;            // q-row within wave
  const int q32  = lane >> 5;
  // XCD-aware remap: dispatch id = x + 16y + 256z; XCD = id % 8 (round-robin).
  // Decode so blocks sharing (h,b) [and thus K/V] are congruent mod 64 -> same XCD.
  const int flat = blockIdx.x + (blockIdx.y << 4) + (blockIdx.z << 8);
  const int qt = flat >> 6;              // 16 q-tiles, consecutive mod-64 -> same XCD
  const int h  = flat & 15;
  const int b  = (flat >> 4) & 3;

  const f16* Qb  = qkv + (size_t)b * SEQ * QKV_LD + h * HDIM;
  const f16* Vtb = vt + (size_t)(b * 16 + h) * HDIM * SEQ;
  const int qrow = qt * 128 + wave * 32 + n;

  // Q as B-fragments: B[k=d][n=qrow], lane holds d = cc*16 + q32*8 + j.
  // Pre-scaled by 0.125*log2(e); exp shift folded into acc init.
  f16x8 qf[4];
  {
    const f16* qp = Qb + (size_t)qrow * QKV_LD + q32 * 8;
    const f16 sc = (f16)(0.125f * 1.44269504f);
    #pragma unroll
    for (int cc = 0; cc < 4; ++cc) qf[cc] = *(const f16x8*)(qp + cc * 16) * sc;
  }

  // staging: running pointers, advanced 64 keys per tile
  const int r0 = tid >> 3, c0 = tid & 7;
  const f16* gK0 = Qb + 1024 + (size_t)r0 * QKV_LD + (c0 ^ swz5(r0)) * 8;
  const f16* gK1 = Qb + 1024 + (size_t)(r0 + 32) * QKV_LD + (c0 ^ swz5(r0 + 32)) * 8;
  const f16* gV0 = Vtb + (size_t)r0 * SEQ + (c0 ^ swz5(r0)) * 8;
  const f16* gV1 = Vtb + (size_t)(r0 + 32) * SEQ + (c0 ^ swz5(r0 + 32)) * 8;
  const int lb = __builtin_amdgcn_readfirstlane((tid & ~63) * 16);

  auto stage = [&](int bufbyte) {
    char* base = (char*)smem + bufbyte + lb;
    __builtin_amdgcn_global_load_lds((const __attribute__((address_space(1))) void*)gK0,
                                     (__attribute__((address_space(3))) void*)(base), 16, 0, 0);
    __builtin_amdgcn_global_load_lds((const __attribute__((address_space(1))) void*)gK1,
                                     (__attribute__((address_space(3))) void*)(base + 4096), 16, 0, 0);
    __builtin_amdgcn_global_load_lds((const __attribute__((address_space(1))) void*)gV0,
                                     (__attribute__((address_space(3))) void*)(base + 8192), 16, 0, 0);
    __builtin_amdgcn_global_load_lds((const __attribute__((address_space(1))) void*)gV1,
                                     (__attribute__((address_space(3))) void*)(base + 12288), 16, 0, 0);
    gK0 += 64 * QKV_LD; gK1 += 64 * QKV_LD; gV0 += 64; gV1 += 64;
  };

  f32x16 ot[2];
  #pragma unroll
  for (int db = 0; db < 2; ++db)
    #pragma unroll
    for (int i = 0; i < 16; ++i) ot[db][i] = 0.f;
  float ls = 0.f;

  auto compute = [&](int bufe) {           // bufe in f16 elements
    const f16* sK = smem + bufe;           // [64 key][64 d], swz5 granules
    const f16* sV = smem + bufe + 4096;    // [64 d][64 key], swz5 granules
    f16x4 p[2][4];
    #pragma unroll
    for (int kc = 0; kc < 2; ++kc) {
      f32x16 st;
      #pragma unroll
      for (int i = 0; i < 16; ++i) st[i] = -2.8853901817f;   // -2*log2(e)
      __builtin_amdgcn_s_setprio(1);
      #pragma unroll
      for (int cc = 0; cc < 4; ++cc) {
        int row = kc * 32 + n;
        f16x8 kf = *(const f16x8*)&sK[row * 64 + (((cc * 2 + q32) ^ swz5(row)) * 8)];
        st = __builtin_amdgcn_mfma_f32_32x32x16_f16(kf, qf[cc], st, 0, 0, 0);
      }
      __builtin_amdgcn_s_setprio(0);
      // p[kc][g] holds keys (in-half) 8g + 4*q32 + {0..3} of this lane's qrow
      #pragma unroll
      for (int g = 0; g < 4; ++g) {
        float e0 = EXP2(st[4 * g + 0]);
        float e1 = EXP2(st[4 * g + 1]);
        float e2 = EXP2(st[4 * g + 2]);
        float e3 = EXP2(st[4 * g + 3]);
        ls += (e0 + e1) + (e2 + e3);
        p[kc][g] = (f16x4){ (f16)e0, (f16)e1, (f16)e2, (f16)e3 };
      }
    }
    // PV with permuted k-slot->key map; B-frag = lane's own e-quads;
    // V A-frag = data granules {2cc, 2cc+1} at physical {h, h^1}, h = 2cc ^ swz5(row)
    __builtin_amdgcn_s_setprio(1);
    #pragma unroll
    for (int db = 0; db < 2; ++db) {
      int row = db * 32 + n;
      int fr = swz5(row);
      const f16* vrow = &sV[row * 64];
      #pragma unroll
      for (int cc = 0; cc < 4; ++cc) {
        int hg = (2 * cc) ^ fr;
        f16x4 vlo = *(const f16x4*)&vrow[hg * 8 + q32 * 4];
        f16x4 vhi = *(const f16x4*)&vrow[(hg ^ 1) * 8 + q32 * 4];
        f16x8 vf = __builtin_shufflevector(vlo, vhi, 0, 1, 2, 3, 4, 5, 6, 7);
        f16x8 pf = __builtin_shufflevector(p[cc >> 1][2 * (cc & 1)],
                                           p[cc >> 1][2 * (cc & 1) + 1],
                                           0, 1, 2, 3, 4, 5, 6, 7);
        ot[db] = __builtin_amdgcn_mfma_f32_32x32x16_f16(vf, pf, ot[db], 0, 0, 0);
      }
    }
    __builtin_amdgcn_s_setprio(0);
  };

  // double-buffered K-loop: loads for tile t+1 fly during compute(t)
  stage(0);
  #pragma unroll 1
  for (int it = 0; it < 32; it += 2) {
    __syncthreads();                 // drains loads into buf0; all waves done reading buf1
    stage(16384);                    // tile it+1 -> buf1
    compute(0);                      // tile it from buf0
    __syncthreads();                 // drains loads into buf1; all waves done reading buf0
    if (it + 2 < 32) stage(0);       // tile it+2 -> buf0
    compute(8192);                   // tile it+1 from buf1
  }

  // full row-sum: this lane's partial + partner half's partial
  ls += __shfl_xor(ls, 32);
  float inv = 1.0f / ls;

  // Ot -> sO[128 qrow][64 d] (f16, swz5), then coalesced global store.
  // sO = buf0 region: all waves finished reading buf0 at the last mid-loop barrier.
  f16* sO = smem;
  int nl = wave * 32 + n;
  int fo = swz5(nl);
  #pragma unroll
  for (int db = 0; db < 2; ++db)
    #pragma unroll
    for (int g = 0; g < 4; ++g) {
      f16x4 o = { (f16)(ot[db][4 * g + 0] * inv), (f16)(ot[db][4 * g + 1] * inv),
                  (f16)(ot[db][4 * g + 2] * inv), (f16)(ot[db][4 * g + 3] * inv) };
      *(f16x4*)&sO[nl * 64 + (((db * 4 + g) ^ fo) * 8) + q32 * 4] = o;
    }
  __syncthreads();
  #pragma unroll
  for (int issue = 0; issue < 4; ++issue) {
    int g = issue * 256 + tid;
    int rr = g >> 3, sg = g & 7;
    f16x8 v = *(const f16x8*)&sO[rr * 64 + ((sg ^ swz5(rr)) * 8)];
    *(f16x8*)&ctx[(size_t)(b * SEQ + qt * 128 + rr) * KDIM + h * HDIM + sg * 8] = v;
  }
}

// ---------------- launch ----------------
// ws layout (bytes):
//   0        : X16 slot0 (16.78MB)  -> later: ctx (f16)
//   16777216 : X16 slot1 (16.78MB)  -> later: Vt [b][h][64][2048]
//   33554432 : X16 slot2 (16.78MB)
//   50331648 : qkvT  (3072x1024 f16, 6MB)
//   56623104 : woT   (1024x1024 f16, 2MB)
//   58720256 : b3    (3072 f32)
//   58736640 : QKV   (8192x3072 f16, 48MB)
extern "C" void kernel_launch(void* const* d_in, const int* in_sizes, int n_in,
                              void* d_out, int out_size, void* d_ws, size_t ws_size,
                              hipStream_t stream) {
  (void)in_sizes; (void)n_in; (void)out_size; (void)ws_size;
  const float* query = (const float*)d_in[0];
  const float* key_  = (const float*)d_in[1];
  const float* value = (const float*)d_in[2];
  const float* wq = (const float*)d_in[3];
  const float* bq = (const float*)d_in[4];
  const float* wk = (const float*)d_in[5];
  const float* bk = (const float*)d_in[6];
  const float* wv = (const float*)d_in[7];
  const float* bv = (const float*)d_in[8];
  const float* wo = (const float*)d_in[9];
  const float* bo = (const float*)d_in[10];
  float* out = (float*)d_out;

  char* ws = (char*)d_ws;
  f16*   X16  = (f16*)(ws);
  f16*   qkvT = (f16*)(ws + 50331648);
  f16*   woT  = (f16*)(ws + 56623104);
  float* b3   = (float*)(ws + 58720256);
  f16*   QKV  = (f16*)(ws + 58736640);
  f16*   ctx  = (f16*)(ws);                   // aliases X16 slot0 (dead after QKV GEMM)
  f16*   Vt   = (f16*)(ws + 16777216);        // aliases X16 slot1 (dead after QKV GEMM)

  cast3_k<<<dim3(8192, 3), 256, 0, stream>>>(query, key_, value, X16);
  transpose_cast_k<<<dim3(32, 32), dim3(32, 8), 0, stream>>>(wq, qkvT);
  transpose_cast_k<<<dim3(32, 32), dim3(32, 8), 0, stream>>>(wk, qkvT + 1048576);
  transpose_cast_k<<<dim3(32, 32), dim3(32, 8), 0, stream>>>(wv, qkvT + 2097152);
  transpose_cast_k<<<dim3(32, 32), dim3(32, 8), 0, stream>>>(wo, woT);
  concat3_k<<<12, 256, 0, stream>>>(bq, bk, bv, b3);

  gemm_k<true><<<dim3(64, 8, 3), 256, 0, stream>>>(X16, (size_t)8388608, qkvT, b3, (void*)QKV, QKV_LD);
  vtrans_k<<<dim3(32, 16, 4), 256, 0, stream>>>(QKV, Vt);
  attn_k<<<dim3(16, 16, 4), 256, 0, stream>>>(QKV, Vt, ctx);
  gemm_k<false><<<dim3(64, 8, 1), 256, 0, stream>>>(ctx, (size_t)0, woT, bo, (void*)out, 1024);
}